// Round 6
// baseline (1891.187 us; speedup 1.0000x reference)
//
#include <hip/hip_runtime.h>
#include <hip/hip_bf16.h>

// TaylorMap, symmetric-packed quadratic, uniform-9 pair stream (bf16).
// R18 = R12 inner loop VERBATIM (proven zero-spill shape) at DOUBLE
// occupancy: 1024-thread blocks, 16 waves = 4/SIMD (vs 2/SIMD since R12).
//   - Wave (t,g): t = w&3 -> SIMD s hosts the 4 waves of tile s, streaming
//     DISJOINT K-quarters (no L1 duplication); g = w>>2 = K-quarter.
//   - Each wave: ONE PAIRS(BK=g) block of 16 pairs, both column-groups
//     (acc0/acc1) -- per-wave register state identical to R12, fits the
//     128-VGPR cap that 4 waves/SIMD requires (m69: 16 waves/CU @128).
//   - K-merge: g1,g2,g3 publish to sc_lds[3][2][...] (104 KB; total LDS
//     150.5 KB), g0 merges + writes x/out. Still 3 barriers/step.
// Rationale: R13 (reg pipeline, spilled), R14 (skew, null), R15 (barrier
// drain, null), R16/R17 (DMA path, serialization/barrier cost) all failed
// to move the ~31 B/cyc/CU fill rate at 2 waves/SIMD. L2->CU supports
// ~60 B/cyc/CU (m56), so the path is HALF idle -- MLP starvation from the
// immediate-consume reload pattern (~9 loads in flight/wave, WAR-gated).
// This round doubles independent load-issuing waves per SIMD instead of
// rescheduling within them. MFMA floor unchanged (1168/SIMD/step).

#define DSTATE 128
#define BATCH  16384
#define NSTEPS 7
#define BT     64
#define NSL    585          // slices per d-tile: 64*9 pair + 8 linear + 1 pad

typedef __attribute__((ext_vector_type(8)))  short  short8;   // 8 bf16 = 4 VGPRs
typedef __attribute__((ext_vector_type(16))) float  f32x16;   // MFMA 32x32 C/D

__device__ __forceinline__ unsigned short f2bf(float f){
    unsigned int u = __float_as_uint(f);
    u += 0x7fff + ((u >> 16) & 1);          // RNE
    return (unsigned short)(u >> 16);
}

// lgkmcnt-only workgroup barrier: drains LDS ops, NOT the vmem queue
// (R15-verified safe: all cross-wave deps at these barriers are LDS).
__device__ __forceinline__ void barrier_lgkm(){
    asm volatile("s_waitcnt lgkmcnt(0)" ::: "memory");
    __builtin_amdgcn_s_barrier();
}

// Pack symmetric-folded W into bf16 MFMA-A fragments, uniform-9 pair stream.
// Pair p at positions 9p..9p+8: first 8-(p>>4) slices are row p (j-blocks
// p>>4..7), remaining 1+(p>>4) are row 127-p (j-blocks 7-(p>>4)..7).
// Fragment layout: A[m][k], m=lane&31 -> d=32t+m, k=(lane>>5)*8+e -> j=16*s+k.
__global__ void prep_kernel(const float* __restrict__ W, short8* __restrict__ A){
    int gid = blockIdx.x * 256 + threadIdx.x;
    const int ntotal = 4 * 130 * 8 * 64;
    if (gid >= ntotal) return;
    int lane = gid & 63; int r = gid >> 6;
    int s = r & 7;  r >>= 3;
    int row = r % 130;
    int t   = r / 130;
    int d  = t * 32 + (lane & 31);
    int kb = (lane >> 5) * 8;
    int dst;
    bool zero = false;
    if (row < 64){
        int sl = row >> 4;
        if (s < sl) return;
        dst = t * NSL + 9 * row + (s - sl);
    } else if (row < 128){
        int p  = 127 - row;
        int sl = row >> 4;
        if (s < sl) return;
        int ca = 8 - (p >> 4);
        dst = t * NSL + 9 * p + ca + (s - sl);
    } else if (row == 128){
        dst = t * NSL + 576 + s;               // linear (W1) row
    } else {
        if (s) return;                         // zero pad slice
        dst = t * NSL + 584;
        zero = true;
    }
    union { short8 v; unsigned short u[8]; } fr;
#pragma unroll
    for (int e = 0; e < 8; ++e){
        int j = s * 16 + kb + e;
        float v;
        if (zero) v = 0.0f;
        else if (row < 128){
            if      (j < row)  v = 0.0f;
            else if (j == row) v = W[(129 + 128 * row + j) * 128 + d];
            else               v = W[(129 + 128 * row + j) * 128 + d]
                                 + W[(129 + 128 * j + row) * 128 + d];
        } else {
            v = W[(1 + j) * 128 + d];
        }
        fr.u[e] = f2bf(v);
    }
    A[(size_t)dst * 64 + lane] = fr.v;
}

__global__ __launch_bounds__(1024)
void taylor_kernel(const float* __restrict__ X, const float* __restrict__ W,
                   const float* __restrict__ tini, const float* __restrict__ lini,
                   const short8* __restrict__ A, float* __restrict__ out)
{
    __shared__ float  x_lds[DSTATE * BT];      // fp32 master state [d][b], 32 KB
    __shared__ float  w0_lds[DSTATE];          // 0.5 KB
    __shared__ short8 bpack[2 * 8 * 64];       // B frags, 2 col-groups x 8, 16 KB
    __shared__ float  sc_lds[3][2][4 * 64 * 17]; // K-merge: 3 pubs x 2 cg, 104 KB

    const int tid  = threadIdx.x;
    const int lane = tid & 63;
    const int w    = tid >> 6;                 // 0..15
    const int t    = w & 3;                    // d-tile (= SIMD id -> co-residents share t)
    const int g    = w >> 2;                   // K-quarter (pairs 16g..16g+15)
    const int ln   = lane & 31;
    const int hi   = lane >> 5;
    const int b0   = blockIdx.x * BT;

    // ---- init x0 = [X | t_init | l_init] ----
#pragma unroll
    for (int it = 0; it < 8; ++it){
        int entry = tid + it * 1024;           // entry = b*128 + d
        int b = entry >> 7, d = entry & 127;
        float v;
        if      (d < 120) v = X[(b0 + b) * 120 + d];
        else if (d < 124) v = tini[d - 120];
        else              v = lini[d - 124];
        x_lds[d * BT + b] = v;
    }
    if (tid < DSTATE) w0_lds[tid] = W[tid];

    // wave's quarter-stream base: pairs 16g.. (g3's tail runs into linear row)
    const short8* const Aw = A + ((size_t)t * NSL + (size_t)g * 144) * 64 + lane;
    const f32x16 zero16 = {};

#pragma unroll 1
    for (int step = 0; step < NSTEPS; ++step){
        barrier_lgkm();                        // (A) x_lds stable

        // last-step pruning: only d-tile 3 feeds out dims 120..123
        const bool active = (step < NSTEPS - 1) || (t == 3);

        const short8* ap = Aw;
        short8 abuf[9];
        if (active){
#pragma unroll
            for (int s = 0; s < 9; ++s) abuf[s] = ap[s * 64];
            ap += 9 * 64;
        }

        // ---- build bpack (1024 frags, 1 per thread) while loads fly ----
        {
            int f  = tid;
            int gg = f >> 9, s = (f >> 6) & 7, l = f & 63;
            int c  = gg * 32 + (l & 31);
            int jb = 16 * s + 8 * (l >> 5);
            union { short8 v; unsigned short u[8]; } fr;
#pragma unroll
            for (int e = 0; e < 8; ++e)
                fr.u[e] = f2bf(x_lds[(jb + e) * BT + c]);
            bpack[f] = fr.v;
        }

        // ---- acc: g0 carries x_old + W0 for both col-groups; g1..g3 zero ----
        f32x16 acc0, acc1;
        if (active){
            if (g == 0){
#pragma unroll
                for (int r = 0; r < 16; ++r){
                    int d = 32 * t + (r & 3) + 8 * (r >> 2) + 4 * hi;
                    acc0[r] = x_lds[d * BT + ln]      + w0_lds[d];
                    acc1[r] = x_lds[d * BT + 32 + ln] + w0_lds[d];
                }
            } else {
#pragma unroll
                for (int r = 0; r < 16; ++r){ acc0[r] = 0.f; acc1[r] = 0.f; }
            }
        }

        barrier_lgkm();                        // (B) bpack visible

        if (active){
            short8 bfrag0[8], bfrag1[8];       // B reg-cache for this BK block

            // R12 core, verbatim: pair p=16*BK+q, rows (p,127-p). Y: slices
            // 0..7-BK (j-blocks BK..7); Z: slices 8-BK..8 (bfrag 7-2BK+s).
            // abuf[s] reloaded for the NEXT pair right after its consumers.
            // q=15 trailing reloads read pair 16(BK+1) (next quarter /
            // linear row) -- in-bounds; g3's feed its linear chain.
#define PAIRS(BK)                                                               \
            {                                                                   \
                _Pragma("unroll")                                               \
                for (int s = 0; s < 8 - (BK); ++s){                             \
                    bfrag0[s] = bpack[((BK) + s) * 64 + lane];                  \
                    bfrag1[s] = bpack[512 + ((BK) + s) * 64 + lane];            \
                }                                                               \
                _Pragma("unroll 2")                                             \
                for (int q = 0; q < 16; ++q){                                   \
                    const int p = 16 * (BK) + q;                                \
                    float s0a = x_lds[p * BT + ln];                             \
                    float s0b = x_lds[p * BT + 32 + ln];                        \
                    float s1a = x_lds[(127 - p) * BT + ln];                     \
                    float s1b = x_lds[(127 - p) * BT + 32 + ln];                \
                    f32x16 Y0, Y1;                                              \
                    _Pragma("unroll")                                           \
                    for (int s = 0; s < 8 - (BK); ++s){                         \
                        Y0 = __builtin_amdgcn_mfma_f32_32x32x16_bf16(abuf[s], bfrag0[s], s ? Y0 : zero16, 0, 0, 0); \
                        Y1 = __builtin_amdgcn_mfma_f32_32x32x16_bf16(abuf[s], bfrag1[s], s ? Y1 : zero16, 0, 0, 0); \
                        abuf[s] = ap[s * 64];                                   \
                    }                                                           \
                    acc0 += s0a * Y0;                                           \
                    acc1 += s0b * Y1;                                           \
                    f32x16 Z0, Z1;                                              \
                    _Pragma("unroll")                                           \
                    for (int s = 0; s < 1 + (BK); ++s){                         \
                        Z0 = __builtin_amdgcn_mfma_f32_32x32x16_bf16(abuf[8 - (BK) + s], bfrag0[7 - 2 * (BK) + s], s ? Z0 : zero16, 0, 0, 0); \
                        Z1 = __builtin_amdgcn_mfma_f32_32x32x16_bf16(abuf[8 - (BK) + s], bfrag1[7 - 2 * (BK) + s], s ? Z1 : zero16, 0, 0, 0); \
                        abuf[8 - (BK) + s] = ap[(8 - (BK) + s) * 64];           \
                    }                                                           \
                    acc0 += s1a * Z0;                                           \
                    acc1 += s1b * Z1;                                           \
                    ap += 9 * 64;                                               \
                }                                                               \
            }

            if      (g == 0){ PAIRS(0) }
            else if (g == 1){ PAIRS(1) }
            else if (g == 2){ PAIRS(2) }
            else {
                PAIRS(3)
                // pair 63's trailing reloads pulled slices 576..584 (linear
                // row + pad) into abuf -- consumed here, nothing wasted.
                // linear (W1) row: scale==1 -> accumulate DIRECTLY into acc
                // via the MFMA C-operand.
#pragma unroll
                for (int s = 0; s < 8; ++s){
                    bfrag0[s] = bpack[s * 64 + lane];
                    bfrag1[s] = bpack[512 + s * 64 + lane];
                }
#pragma unroll
                for (int s = 0; s < 8; ++s){
                    acc0 = __builtin_amdgcn_mfma_f32_32x32x16_bf16(abuf[s], bfrag0[s], acc0, 0, 0, 0);
                    acc1 = __builtin_amdgcn_mfma_f32_32x32x16_bf16(abuf[s], bfrag1[s], acc1, 0, 0, 0);
                }
            }
#undef PAIRS
            if (g >= 1){
                // publish K-quarter partials (both col-groups)
#pragma unroll
                for (int r = 0; r < 16; ++r){
                    sc_lds[g - 1][0][(t * 64 + lane) * 17 + r] = acc0[r];
                    sc_lds[g - 1][1][(t * 64 + lane) * 17 + r] = acc1[r];
                }
            }
        }

        barrier_lgkm();                        // (C) reads done + scratch visible
        if (active && g == 0){
#pragma unroll
            for (int r = 0; r < 16; ++r){
                int i = (t * 64 + lane) * 17 + r;
                acc0[r] += sc_lds[0][0][i] + sc_lds[1][0][i] + sc_lds[2][0][i];
                acc1[r] += sc_lds[0][1][i] + sc_lds[1][1][i] + sc_lds[2][1][i];
            }
            if (step < NSTEPS - 1){
#pragma unroll
                for (int r = 0; r < 16; ++r){
                    int d = 32 * t + (r & 3) + 8 * (r >> 2) + 4 * hi;
                    x_lds[d * BT + ln]      = acc0[r];
                    x_lds[d * BT + 32 + ln] = acc1[r];
                }
            } else if (hi == 0){
                // out dims 120..123 -> tile 3, regs 12..15 @ hi==0
                *(float4*)(out + (size_t)(b0 + ln) * 4) =
                    make_float4(acc0[12], acc0[13], acc0[14], acc0[15]);
                *(float4*)(out + (size_t)(b0 + 32 + ln) * 4) =
                    make_float4(acc1[12], acc1[13], acc1[14], acc1[15]);
            }
        }
        // next iteration's barrier (A) orders g0's x write vs others' reads
    }
}

extern "C" void kernel_launch(void* const* d_in, const int* in_sizes, int n_in,
                              void* d_out, int out_size, void* d_ws, size_t ws_size,
                              hipStream_t stream)
{
    const float* X  = (const float*)d_in[0];
    const float* W  = (const float*)d_in[1];
    const float* ti = (const float*)d_in[2];
    const float* li = (const float*)d_in[3];
    float* out      = (float*)d_out;
    short8* A       = (short8*)d_ws;           // 4*585*64*16 B = 2.40 MB

    const int ntotal = 4 * 130 * 8 * 64;
    prep_kernel<<<(ntotal + 255) / 256, 256, 0, stream>>>(W, A);
    taylor_kernel<<<BATCH / BT, 1024, 0, stream>>>(X, W, ti, li, A, out);
}